// Round 1
// baseline (1334.708 us; speedup 1.0000x reference)
//
#include <hip/hip_runtime.h>
#include <math.h>

// Problem constants (fixed by reference setup_inputs):
//   x:    (B=16, C=64, H=512, W=512) float32
//   mask: (B=16, 1,    H=512, W=512) int32 (0/1)
//   out:  (B=16, C=64) float32
#define BB 16
#define CC 64
#define HW (512 * 512)      // 262144 spatial elements per (b,c) plane
#define SS 8                // spatial splits per plane
#define CH (HW / SS)        // 32768 elements per chunk
#define TPB 256
#define VEC_ITERS (CH / 4 / TPB)  // 32 float4 iterations per thread

// Kernel 1: each block reduces one (b, c, s) chunk to a single partial max.
// Grid ordering: c fastest -> 64 consecutive blocks share one mask chunk
// (L2/L3 reuse; mask is only 16.8 MB total, fully L3-resident).
__global__ __launch_bounds__(TPB) void maskpool_partial(
    const float* __restrict__ x,
    const int* __restrict__ mask,
    float* __restrict__ partial) {
  const int blk = blockIdx.x;
  const int b = blk / (SS * CC);
  const int rem = blk % (SS * CC);
  const int s = rem / CC;
  const int c = rem % CC;

  const float4* __restrict__ xp = reinterpret_cast<const float4*>(
      x + (size_t)(b * CC + c) * HW + (size_t)s * CH);
  const int4* __restrict__ mp = reinterpret_cast<const int4*>(
      mask + (size_t)b * HW + (size_t)s * CH);

  const int t = threadIdx.x;
  float acc = -INFINITY;

#pragma unroll 4
  for (int i = 0; i < VEC_ITERS; ++i) {
    const float4 xv = xp[t + i * TPB];
    const int4 mv = mp[t + i * TPB];
    acc = fmaxf(acc, mv.x ? xv.x : -INFINITY);
    acc = fmaxf(acc, mv.y ? xv.y : -INFINITY);
    acc = fmaxf(acc, mv.z ? xv.z : -INFINITY);
    acc = fmaxf(acc, mv.w ? xv.w : -INFINITY);
  }

  // Wave-64 shuffle max reduction.
#pragma unroll
  for (int off = 32; off > 0; off >>= 1)
    acc = fmaxf(acc, __shfl_down(acc, off));

  __shared__ float wred[TPB / 64];
  const int wave = t >> 6;
  if ((t & 63) == 0) wred[wave] = acc;
  __syncthreads();
  if (t == 0) {
    float m = fmaxf(fmaxf(wred[0], wred[1]), fmaxf(wred[2], wred[3]));
    partial[(size_t)(b * CC + c) * SS + s] = m;
  }
}

// Kernel 2: reduce SS partials per (b,c); empty mask (max == -inf) -> 0.
__global__ __launch_bounds__(TPB) void maskpool_final(
    const float* __restrict__ partial, float* __restrict__ out) {
  const int tid = blockIdx.x * blockDim.x + threadIdx.x;
  if (tid < BB * CC) {
    float m = -INFINITY;
#pragma unroll
    for (int s = 0; s < SS; ++s) m = fmaxf(m, partial[(size_t)tid * SS + s]);
    out[tid] = (m == -INFINITY) ? 0.0f : m;
  }
}

extern "C" void kernel_launch(void* const* d_in, const int* in_sizes, int n_in,
                              void* d_out, int out_size, void* d_ws,
                              size_t ws_size, hipStream_t stream) {
  const float* x = (const float*)d_in[0];
  const int* mask = (const int*)d_in[1];
  float* out = (float*)d_out;
  float* partial = (float*)d_ws;  // BB*CC*SS floats = 32 KB

  const int nblk1 = BB * CC * SS;  // 8192
  maskpool_partial<<<nblk1, TPB, 0, stream>>>(x, mask, partial);

  const int nblk2 = (BB * CC + TPB - 1) / TPB;  // 4
  maskpool_final<<<nblk2, TPB, 0, stream>>>(partial, out);
}